// Round 19
// baseline (334.396 us; speedup 1.0000x reference)
//
#include <hip/hip_runtime.h>
#include <hip/hip_fp16.h>
#include <math.h>

typedef _Float16 f16;
typedef _Float16 f16x4 __attribute__((ext_vector_type(4)));
typedef _Float16 f16x8 __attribute__((ext_vector_type(8)));
typedef float f32x4 __attribute__((ext_vector_type(4)));
typedef float f32x4e __attribute__((ext_vector_type(4)));

#define GLOAD_LDS16(g, l)                                                                  \
    __builtin_amdgcn_global_load_lds((const __attribute__((address_space(1))) void*)(g),   \
                                     (__attribute__((address_space(3))) void*)(l), 16, 0, 0)

__device__ __forceinline__ void cast16(const float* __restrict__ src, f16* __restrict__ dst,
                                       long long i)
{
    const f32x4e* sp = (const f32x4e*)(src + i * 16);
    f32x4e a = __builtin_nontemporal_load(sp + 0);
    f32x4e b = __builtin_nontemporal_load(sp + 1);
    f32x4e c = __builtin_nontemporal_load(sp + 2);
    f32x4e d4 = __builtin_nontemporal_load(sp + 3);
    f16x8 lo = {(f16)a[0], (f16)a[1], (f16)a[2], (f16)a[3],
                (f16)b[0], (f16)b[1], (f16)b[2], (f16)b[3]};
    f16x8 hi = {(f16)c[0], (f16)c[1], (f16)c[2], (f16)c[3],
                (f16)d4[0], (f16)d4[1], (f16)d4[2], (f16)d4[3]};
    f16x8* dp = (f16x8*)(dst + i * 16);
    dp[0] = lo;
    dp[1] = hi;
}

// W prep: z=0/1 transpose-cast Wq->whA, Wk->whB; z=2 plain cast Wv -> whC.
__global__ __launch_bounds__(256) void prep_w_kernel(const float* __restrict__ Wq,
                                                     const float* __restrict__ Wk,
                                                     const float* __restrict__ Wv,
                                                     f16* __restrict__ dA,
                                                     f16* __restrict__ dB,
                                                     f16* __restrict__ dC)
{
    __shared__ f16 tile[64][72];
    const int z = blockIdx.z;
    const int t = threadIdx.x;
    if (z == 2) {
        const long long i = (long long)(blockIdx.y * 16 + blockIdx.x) * 256 + t;  // < 65536
        cast16(Wv, dC, i);
        return;
    }
    const float* src = z ? Wk : Wq;
    f16* dst = z ? dB : dA;
    const int h0 = blockIdx.x * 64, o0 = blockIdx.y * 64;
    const int r = t >> 2, c = (t & 3) * 16;
    const float* sp = src + (long long)(o0 + r) * 1024 + h0 + c;
    float4 v0 = *(const float4*)(sp + 0);
    float4 v1 = *(const float4*)(sp + 4);
    float4 v2 = *(const float4*)(sp + 8);
    float4 v3 = *(const float4*)(sp + 12);
    *(f16x4*)&tile[r][c]      = (f16x4){(f16)v0.x, (f16)v0.y, (f16)v0.z, (f16)v0.w};
    *(f16x4*)&tile[r][c + 4]  = (f16x4){(f16)v1.x, (f16)v1.y, (f16)v1.z, (f16)v1.w};
    *(f16x4*)&tile[r][c + 8]  = (f16x4){(f16)v2.x, (f16)v2.y, (f16)v2.z, (f16)v2.w};
    *(f16x4*)&tile[r][c + 12] = (f16x4){(f16)v3.x, (f16)v3.y, (f16)v3.z, (f16)v3.w};
    __syncthreads();
    f16 buf[16];
#pragma unroll
    for (int j = 0; j < 16; j++) buf[j] = tile[c + j][r];
    f16* dp = dst + (long long)(h0 + r) * 1024 + o0 + c;
    *(f16x8*)(dp)     = *(f16x8*)&buf[0];
    *(f16x8*)(dp + 8) = *(f16x8*)&buf[8];
}

// Fused: z=0 cast Xk, z=1 cast Xv; z=2: M = WqT @ WkT^T (64 blocks).
__global__ __launch_bounds__(256) void fused_cast_m_kernel(
    const float* __restrict__ Xk, const float* __restrict__ Xv,
    f16* __restrict__ dXk, f16* __restrict__ dXv,
    const f16* __restrict__ whA, const f16* __restrict__ whB, f16* __restrict__ whD)
{
    __shared__ __align__(16) f16 msmem[128 * 32 * 2];   // 16 KB (z=2 only)
    const int z = blockIdx.z;
    const int tid = threadIdx.x;
    if (z == 0) { cast16(Xk, dXk, (long long)blockIdx.x * 256 + tid); return; }
    if (z == 1) { cast16(Xv, dXv, (long long)blockIdx.x * 256 + tid); return; }
    if (blockIdx.x >= 64) return;   // uniform block exit, before any barrier

    const int b = blockIdx.x;
    const int by = b >> 3, bx = b & 7;
    const char* pA = (const char*)(whA + (long long)by * 128 * 1024);
    const char* pB = (const char*)(whB + (long long)bx * 128 * 1024);
    const int w = tid >> 6, l = tid & 63;
    const int wr = w >> 1, wc = w & 1;
    f32x4 acc[4][4];
#pragma unroll
    for (int i = 0; i < 4; i++)
#pragma unroll
        for (int j = 0; j < 4; j++) acc[i][j] = (f32x4){0.f, 0.f, 0.f, 0.f};
    const int lr = l & 15, lkb = (l >> 4) * 16;

    for (int t = 0; t < 32; ++t) {
        const long long kb = (long long)t * 64;   // 32 f16 = 64 B per row
#pragma unroll
        for (int i = 0; i < 2; i++) {
            const int c = i * 256 + tid;
            const int row = c >> 2;
            const int col = ((c & 3) * 16) ^ ((row & 3) << 4);
            GLOAD_LDS16(pA + (long long)row * 2048 + kb + col, &msmem[(long long)c * 8]);
            GLOAD_LDS16(pB + (long long)row * 2048 + kb + col, &msmem[4096 + (long long)c * 8]);
        }
        __syncthreads();
        f16x8 af[4], bf[4];
#pragma unroll
        for (int f = 0; f < 4; f++) {
            const int ra = wr * 64 + f * 16 + lr;
            const int rb = wc * 64 + f * 16 + lr;
            af[f] = *(const f16x8*)((const char*)&msmem[0] + ra * 64 + (lkb ^ ((ra & 3) << 4)));
            bf[f] = *(const f16x8*)((const char*)&msmem[4096] + rb * 64 + (lkb ^ ((rb & 3) << 4)));
        }
#pragma unroll
        for (int fq = 0; fq < 4; fq++)
#pragma unroll
            for (int fc = 0; fc < 4; fc++)
                acc[fq][fc] = __builtin_amdgcn_mfma_f32_16x16x32_f16(af[fq], bf[fc], acc[fq][fc], 0, 0, 0);
        __syncthreads();
    }
    const int rowl = (l >> 4) * 4;
#pragma unroll
    for (int fq = 0; fq < 4; fq++)
#pragma unroll
        for (int fc = 0; fc < 4; fc++)
#pragma unroll
            for (int i = 0; i < 4; i++)
                whD[(long long)(by * 128 + wr * 64 + fq * 16 + rowl + i) * 1024 +
                    bx * 128 + wc * 64 + fc * 16 + lr] = (f16)acc[fq][fc][i];
}

// ============================================================================
// r10-proven 256x128 / BK=64 single-buffer kernel (used for v-proj and k').
// ============================================================================
template <int OUTF16, int TRANSC, int XQCAST>
__global__ __launch_bounds__(512, 2) void gemm_nt_k(
    const f16* __restrict__ Ab, const f16* __restrict__ Bb, void* __restrict__ Cb,
    int K, int lda, int ldb, int ldc,
    long long sA, long long sB, long long sC, int gx,
    const float* __restrict__ xq_src, f16* __restrict__ xq_dst)
{
    __shared__ __align__(16) f16 smem[256 * 64 + 128 * 64];
    constexpr int B_OFF_E = 256 * 64;
    constexpr int B_OFF_B = B_OFF_E * 2;

    const int tid = threadIdx.x;
    if (XQCAST) {
        if (blockIdx.z == 1) { cast16(xq_src, xq_dst, (long long)blockIdx.x * 512 + tid); return; }
        if (blockIdx.x >= 512) return;   // uniform exit, before any barrier
    }

    const int nwg = XQCAST ? 512 : gridDim.x;
    const int swz = (blockIdx.x & 7) * (nwg >> 3) + (blockIdx.x >> 3);
    const int bx = swz % gx, by = swz / gx;

    const int z = XQCAST ? 0 : blockIdx.z;
    const char* pA = (const char*)(Ab + z * sA + (long long)by * 256 * lda);
    const char* pB = (const char*)(Bb + z * sB + (long long)bx * 128 * ldb);
    const long long lda2 = (long long)lda * 2, ldb2 = (long long)ldb * 2;

    const int w = tid >> 6, l = tid & 63;
    const int wr = w >> 1, wc = w & 1;

    f32x4 acc[4][4];
#pragma unroll
    for (int i = 0; i < 4; i++)
#pragma unroll
        for (int j = 0; j < 4; j++) acc[i][j] = (f32x4){0.f, 0.f, 0.f, 0.f};

    const int lr = l & 15;
    const int lkb = (l >> 4) * 16;

#define FRAG_A16(row, kbyte)                                                              \
    (*(const f16x8*)((const char*)&smem[0] + ((row) * 128) + ((kbyte) ^ (((row) & 7) << 4))))
#define FRAG_B(row, kbyte)                                                                \
    (*(const f16x8*)((const char*)&smem[0] + B_OFF_B + ((row) * 128) + ((kbyte) ^ (((row) & 7) << 4))))

    const int nt = K >> 6;
    for (int t = 0; t < nt; ++t) {
        const long long kb = (long long)t * 128;
#pragma unroll
        for (int i = 0; i < 4; i++) {
            const int c = i * 512 + tid;
            const int row = c >> 3;
            const int col = ((c & 7) * 16) ^ ((row & 7) << 4);
            GLOAD_LDS16(pA + (long long)row * lda2 + kb + col, &smem[(long long)c * 8]);
        }
#pragma unroll
        for (int i = 0; i < 2; i++) {
            const int c = i * 512 + tid;
            const int row = c >> 3;
            const int col = ((c & 7) * 16) ^ ((row & 7) << 4);
            GLOAD_LDS16(pB + (long long)row * ldb2 + kb + col, &smem[B_OFF_E + (long long)c * 8]);
        }
        __syncthreads();

        f16x8 bf[4][2], af[4][2];
#pragma unroll
        for (int fc = 0; fc < 4; fc++)
#pragma unroll
            for (int ks = 0; ks < 2; ks++)
                bf[fc][ks] = FRAG_B(wc * 64 + fc * 16 + lr, ks * 64 + lkb);
#pragma unroll
        for (int fq = 0; fq < 4; fq++)
#pragma unroll
            for (int ks = 0; ks < 2; ks++)
                af[fq][ks] = FRAG_A16(wr * 64 + fq * 16 + lr, ks * 64 + lkb);

#pragma unroll
        for (int fq = 0; fq < 4; fq++)
#pragma unroll
            for (int fc = 0; fc < 4; fc++)
#pragma unroll
                for (int ks = 0; ks < 2; ks++)
                    acc[fq][fc] = __builtin_amdgcn_mfma_f32_16x16x32_f16(
                        af[fq][ks], bf[fc][ks], acc[fq][fc], 0, 0, 0);

        __syncthreads();
    }
#undef FRAG_A16
#undef FRAG_B

    const int row_l = (l >> 4) * 4;
    const long long gr0 = (long long)by * 256 + wr * 64;
    const int gc0 = bx * 128 + wc * 64;

    if (TRANSC) {
        const long long blk_r0 = (long long)by * 256;
        const int b = (int)(blk_r0 >> 11);
        const int s_base = (int)(blk_r0 & 2047);
        f16* vTp = (f16*)Cb + (long long)b * 1024 * 2048;
#pragma unroll
        for (int h = 0; h < 2; h++) {
            __syncthreads();
            if ((wr >> 1) == h) {
                const int s64 = (wr & 1) * 64;
#pragma unroll
                for (int fq = 0; fq < 4; fq++)
#pragma unroll
                    for (int fc = 0; fc < 4; fc++)
#pragma unroll
                        for (int i = 0; i < 4; i++)
                            smem[(wc * 64 + fc * 16 + lr) * 136 + s64 + fq * 16 + row_l + i] =
                                (f16)acc[fq][fc][i];
            }
            __syncthreads();
#pragma unroll
            for (int j = 0; j < 4; j++) {
                const int c = j * 512 + tid;
                const int o = c >> 4, s8 = (c & 15) * 8;
                f16x8 vv = *(const f16x8*)&smem[o * 136 + s8];
                *(f16x8*)&vTp[((long long)(bx * 128 + o)) * 2048 + s_base + h * 128 + s8] = vv;
            }
        }
    } else if (OUTF16) {
        f16* C = (f16*)Cb + z * sC;
#pragma unroll
        for (int fq = 0; fq < 4; fq++)
#pragma unroll
            for (int fc = 0; fc < 4; fc++)
#pragma unroll
                for (int i = 0; i < 4; i++)
                    C[(gr0 + fq * 16 + row_l + i) * ldc + gc0 + fc * 16 + lr] = (f16)acc[fq][fc][i];
    } else {
        float* C = (float*)Cb + z * sC;
#pragma unroll
        for (int fq = 0; fq < 4; fq++)
#pragma unroll
            for (int fc = 0; fc < 4; fc++)
#pragma unroll
                for (int i = 0; i < 4; i++)
                    __builtin_nontemporal_store(
                        acc[fq][fc][i],
                        &C[(gr0 + fq * 16 + row_l + i) * ldc + gc0 + fc * 16 + lr]);
    }
}

// ============================================================================
// m201-faithful 256x256 / BK=64 8-phase kernel (S and PV).  8 waves 2Mx4N,
// 128 KiB LDS (2buf x 2half x [128][64] x {A,B}).  Per phase: {4 A ds_reads
// (+8 B at p0); 1 half-tile stage (2 gload_lds); barrier; 16 MFMA; barrier}.
// Stage schedule from half-tile lifetimes (B dead after p0, A after p3):
//   ph0-1: buf1.A<-t(2i+1) ; ph2-3: buf0.B<-t(2i+2) ;
//   ph4-5: buf0.A<-t(2i+2) ; ph6-7: buf1.B<-t(2i+3)
// Counted waits (invariant: 4 loads outstanding at each K-tile boundary):
//   vmcnt(4) at ph3/ph7 ends; prologue t0 full + t1.B, vmcnt(4); tail vmcnt(0).
// WAR: every stage issues after the barrier retiring its region's last read.
// RAW: FIFO vmcnt drains exactly the half-tiles the next K-tile reads.
// ============================================================================
template <int OUTF16>
__global__ __launch_bounds__(512, 1) void gemm_nt_256(
    const f16* __restrict__ Ab, const f16* __restrict__ Bb, void* __restrict__ Cb,
    int K, int lda, int ldb, int ldc,
    long long sA, long long sB, long long sC, int gx)
{
    __shared__ __align__(16) f16 AS[2][2][128 * 64];
    __shared__ __align__(16) f16 BS[2][2][128 * 64];

    const int nwg = gridDim.x;
    const int swz = (blockIdx.x & 7) * (nwg >> 3) + (blockIdx.x >> 3);
    const int bx = swz % gx, by = swz / gx;
    const int z = blockIdx.z;
    const char* pA = (const char*)(Ab + z * sA + (long long)by * 256 * lda);
    const char* pB = (const char*)(Bb + z * sB + (long long)bx * 256 * ldb);
    const long long lda2 = (long long)lda * 2, ldb2 = (long long)ldb * 2;

    const int tid = threadIdx.x;
    const int w = tid >> 6, l = tid & 63;
    const int wr = w >> 2, wc = w & 3;          // 2M x 4N; per-wave out 128x64

    // staging: per half-tile 2 chunks/thread; chunk c=j*512+tid -> row=c>>3,
    // col=(c&7)*16 bytes; LDS linear dest, global source col inverse-swizzled.
    const int sr0 = tid >> 3;
    const int sr1 = 64 + (tid >> 3);
    const int sc0 = ((tid & 7) * 16) ^ ((sr0 & 7) << 4);
    const int sc1 = ((tid & 7) * 16) ^ ((sr1 & 7) << 4);

#define STAGE_A(buf, h, t)                                                                 \
    do {                                                                                   \
        GLOAD_LDS16(pA + (long long)((h) * 128 + sr0) * lda2 + (long long)(t) * 128 + sc0, \
                    &AS[buf][h][(long long)tid * 8]);                                      \
        GLOAD_LDS16(pA + (long long)((h) * 128 + sr1) * lda2 + (long long)(t) * 128 + sc1, \
                    &AS[buf][h][(long long)(512 + tid) * 8]);                              \
    } while (0)
#define STAGE_B(buf, h, t)                                                                 \
    do {                                                                                   \
        GLOAD_LDS16(pB + (long long)((h) * 128 + sr0) * ldb2 + (long long)(t) * 128 + sc0, \
                    &BS[buf][h][(long long)tid * 8]);                                      \
        GLOAD_LDS16(pB + (long long)((h) * 128 + sr1) * ldb2 + (long long)(t) * 128 + sc1, \
                    &BS[buf][h][(long long)(512 + tid) * 8]);                              \
    } while (0)

#define FRAG_A(buf, r, kbyte)                                                              \
    (*(const f16x8*)((const char*)&AS[buf][(r) >> 7][0] + ((r) & 127) * 128 +              \
                     ((kbyte) ^ (((r) & 7) << 4))))
#define FRAG_Bf(buf, r, kbyte)                                                             \
    (*(const f16x8*)((const char*)&BS[buf][(r) >> 7][0] + ((r) & 127) * 128 +              \
                     ((kbyte) ^ (((r) & 7) << 4))))

    f32x4 acc[8][4];
#pragma unroll
    for (int i = 0; i < 8; i++)
#pragma unroll
        for (int j = 0; j < 4; j++) acc[i][j] = (f32x4){0.f, 0.f, 0.f, 0.f};

    const int lr = l & 15;
    const int lkb = (l >> 4) * 16;

#define PHASE(buf, p, STAGECODE, VMCODE)                                                   \
    do {                                                                                   \
        if ((p) == 0) {                                                                    \
            _Pragma("unroll") for (int fc = 0; fc < 4; fc++)                               \
            _Pragma("unroll") for (int ks = 0; ks < 2; ks++)                               \
                bf[fc][ks] = FRAG_Bf(buf, wc * 64 + fc * 16 + lr, ks * 64 + lkb);          \
        }                                                                                  \
        f16x8 af[2][2];                                                                    \
        _Pragma("unroll") for (int fr = 0; fr < 2; fr++)                                   \
        _Pragma("unroll") for (int ks = 0; ks < 2; ks++)                                   \
            af[fr][ks] = FRAG_A(buf, wr * 128 + (p) * 32 + fr * 16 + lr, ks * 64 + lkb);   \
        STAGECODE;                                                                         \
        __builtin_amdgcn_s_barrier();                                                      \
        __builtin_amdgcn_sched_barrier(0);                                                 \
        __builtin_amdgcn_s_setprio(1);                                                     \
        _Pragma("unroll") for (int fr = 0; fr < 2; fr++)                                   \
        _Pragma("unroll") for (int fc = 0; fc < 4; fc++)                                   \
        _Pragma("unroll") for (int ks = 0; ks < 2; ks++)                                   \
            acc[(p) * 2 + fr][fc] = __builtin_amdgcn_mfma_f32_16x16x32_f16(                \
                af[fr][ks], bf[fc][ks], acc[(p) * 2 + fr][fc], 0, 0, 0);                   \
        __builtin_amdgcn_s_setprio(0);                                                     \
        VMCODE;                                                                            \
        __builtin_amdgcn_s_barrier();                                                      \
        __builtin_amdgcn_sched_barrier(0);                                                 \
    } while (0)

    const int nt = K >> 6;        // K-tiles (even: 16 or 32)
    const int niter = nt >> 1;

    // Prologue: t0 full (A,B) + t1.B ; drain t0, keep t1.B in flight.
    STAGE_A(0, 0, 0); STAGE_A(0, 1, 0);
    STAGE_B(0, 0, 0); STAGE_B(0, 1, 0);
    STAGE_B(1, 0, 1); STAGE_B(1, 1, 1);
    asm volatile("s_waitcnt vmcnt(4)" ::: "memory");
    __builtin_amdgcn_s_barrier();
    __builtin_amdgcn_sched_barrier(0);

    for (int i = 0; i < niter; ++i) {
        const int t1 = 2 * i + 1, t2 = 2 * i + 2, t3 = 2 * i + 3;
        const bool fs = (t2 < nt);
        f16x8 bf[4][2];
        // ---- K-tile 2i from buf0 ----
        PHASE(0, 0, { STAGE_A(1, 0, t1); }, {});
        PHASE(0, 1, { STAGE_A(1, 1, t1); }, {});
        PHASE(0, 2, { if (fs) STAGE_B(0, 0, t2); }, {});
        PHASE(0, 3, { if (fs) STAGE_B(0, 1, t2); },
              {
                  if (fs) asm volatile("s_waitcnt vmcnt(4)" ::: "memory");
                  else    asm volatile("s_waitcnt vmcnt(0)" ::: "memory");
              });
        // ---- K-tile 2i+1 from buf1 ----
        PHASE(1, 0, { if (fs) STAGE_A(0, 0, t2); }, {});
        PHASE(1, 1, { if (fs) STAGE_A(0, 1, t2); }, {});
        PHASE(1, 2, { if (fs) STAGE_B(1, 0, t3); }, {});
        PHASE(1, 3, { if (fs) STAGE_B(1, 1, t3); },
              { if (fs) asm volatile("s_waitcnt vmcnt(4)" ::: "memory"); });
    }
#undef PHASE
#undef STAGE_A
#undef STAGE_B
#undef FRAG_A
#undef FRAG_Bf

    // C/D 16x16 layout: col = lane&15, row = (lane>>4)*4 + i
    const int row_l = (l >> 4) * 4;
    const long long gr0 = (long long)by * 256 + wr * 128;
    const int gc0 = bx * 256 + wc * 64;
    if (OUTF16) {
        f16* C = (f16*)Cb + z * sC;
#pragma unroll
        for (int fq = 0; fq < 8; fq++)
#pragma unroll
            for (int fc = 0; fc < 4; fc++)
#pragma unroll
                for (int i = 0; i < 4; i++)
                    C[(gr0 + fq * 16 + row_l + i) * ldc + gc0 + fc * 16 + lr] = (f16)acc[fq][fc][i];
    } else {
        float* C = (float*)Cb + z * sC;
#pragma unroll
        for (int fq = 0; fq < 8; fq++)
#pragma unroll
            for (int fc = 0; fc < 4; fc++)
#pragma unroll
                for (int i = 0; i < 4; i++)
                    __builtin_nontemporal_store(
                        acc[fq][fc][i],
                        &C[(gr0 + fq * 16 + row_l + i) * ldc + gc0 + fc * 16 + lr]);
    }
}

__device__ __forceinline__ float wred_max(float v) {
#pragma unroll
    for (int o = 32; o > 0; o >>= 1) v = fmaxf(v, __shfl_xor(v, o));
    return v;
}
__device__ __forceinline__ float wred_sum(float v) {
#pragma unroll
    for (int o = 32; o > 0; o >>= 1) v += __shfl_xor(v, o);
    return v;
}

// In-place masked softmax over each 2048-wide score row (fp16).
__global__ __launch_bounds__(256) void softmax_kernel(f16* __restrict__ Sm, const int* __restrict__ mask)
{
    const long long row = blockIdx.x;
    const int b = (int)(row >> 11);
    f16* Srow = Sm + row * 2048;
    const int* mrow = mask + b * 2048;
    const int t = threadIdx.x;
    const int w = t >> 6, l = t & 63;

    f16x8 sv = *(const f16x8*)(Srow + t * 8);
    int4 m0 = *(const int4*)(mrow + t * 8);
    int4 m1 = *(const int4*)(mrow + t * 8 + 4);
    int mk[8] = {m0.x, m0.y, m0.z, m0.w, m1.x, m1.y, m1.z, m1.w};
    float v[8];
#pragma unroll
    for (int j = 0; j < 8; j++) v[j] = (float)sv[j];

    float mx = -INFINITY;
#pragma unroll
    for (int j = 0; j < 8; j++) if (mk[j]) mx = fmaxf(mx, v[j]);
    mx = wred_max(mx);
    __shared__ float redm[4], reds[4];
    if (l == 0) redm[w] = mx;
    __syncthreads();
    mx = fmaxf(fmaxf(redm[0], redm[1]), fmaxf(redm[2], redm[3]));

    if (mx == -INFINITY) {
        // reference: all scores == MASK_FILL -> softmax is exactly uniform
        const f16 u = (f16)(1.0f / 2048.0f);
        f16x8 pv;
#pragma unroll
        for (int j = 0; j < 8; j++) pv[j] = u;
        *(f16x8*)(Srow + t * 8) = pv;
        return;
    }

    float e[8];
    float s = 0.f;
#pragma unroll
    for (int j = 0; j < 8; j++) { e[j] = mk[j] ? expf(v[j] - mx) : 0.f; s += e[j]; }
    s = wred_sum(s);
    if (l == 0) reds[w] = s;
    __syncthreads();
    s = reds[0] + reds[1] + reds[2] + reds[3];
    const float inv = 1.0f / s;
    f16x8 pv;
#pragma unroll
    for (int j = 0; j < 8; j++) pv[j] = (f16)(e[j] * inv);
    *(f16x8*)(Srow + t * 8) = pv;
}

extern "C" void kernel_launch(void* const* d_in, const int* in_sizes, int n_in,
                              void* d_out, int out_size, void* d_ws, size_t ws_size,
                              hipStream_t stream)
{
    const float* query = (const float*)d_in[0];
    const float* keyi  = (const float*)d_in[1];
    const float* value = (const float*)d_in[2];
    const float* Wq    = (const float*)d_in[3];
    const float* Wk    = (const float*)d_in[4];
    const float* Wv    = (const float*)d_in[5];
    const int*   mask  = (const int*)d_in[6];
    float* out = (float*)d_out;

    // Algebra (r14): S = Xq (Wq^T Wk) Xk^T; M = Wq^T Wk; k' = Xk M^T.
    // ws: 5 slots of SH f16 = 167.8 MB (lifetimes as r18, audited).
    const long long SH = (long long)8 * 2048 * 1024;
    f16* slot0 = (f16*)d_ws;
    f16* slot1 = slot0 + SH;
    f16* slot2 = slot0 + 2 * SH;
    f16* slot3 = slot0 + 3 * SH;
    f16* slot4 = slot0 + 4 * SH;
    const long long M1 = 1024 * 1024;
    f16* whA = slot1;            // WqT f16  [h][o]
    f16* whB = slot1 + M1;       // WkT f16  [h][o]
    f16* whC = slot1 + 2 * M1;   // Wv  f16  [o][h]
    f16* whD = slot1 + 3 * M1;   // M = Wq^T Wk, f16 [j][h]
    f16* Pb  = slot0;            // 8*2048*2048 f16 = 2*SH (slot0 + slot1)

    const long long zero = 0;

    // 0) W prep
    prep_w_kernel<<<dim3(16, 16, 3), 256, 0, stream>>>(Wq, Wk, Wv, whA, whB, whC);
    // 1) fused: Xk -> slot0, Xv -> slot3 casts  ∥  M -> whD
    fused_cast_m_kernel<<<dim3(4096, 1, 3), 256, 0, stream>>>(
        keyi, value, slot0, slot3, whA, whB, whD);
    // 2) v-proj with fused transpose: vT -> slot4
    gemm_nt_k<1, 1, 0><<<dim3(512, 1, 1), 512, 0, stream>>>(
        slot3, whC, (void*)slot4, 1024, 1024, 1024, 2048, zero, zero, zero, 8,
        nullptr, nullptr);
    // 3) fused: k' -> slot3  ∥  Xq cast -> slot2
    gemm_nt_k<1, 0, 1><<<dim3(2048, 1, 2), 512, 0, stream>>>(
        slot0, whD, (void*)slot3, 1024, 1024, 1024, 1024, zero, zero, zero, 8,
        query, slot2);
    // 4) S = Xq @ k'^T per batch -> P  (8-phase 256^2 kernel; 64 blocks/z)
    gemm_nt_256<1><<<dim3(64, 1, 8), 512, 0, stream>>>(
        slot2, slot3, (void*)Pb, 1024, 1024, 1024, 2048,
        (long long)2048 * 1024, (long long)2048 * 1024, (long long)2048 * 2048, 8);
    // 5) P = masked softmax(S), in place
    softmax_kernel<<<dim3(16384), 256, 0, stream>>>(Pb, mask);
    // 6) context = P @ vT^T  (8-phase 256^2 kernel, f32 NT stores; 32 blocks/z)
    gemm_nt_256<0><<<dim3(32, 1, 8), 512, 0, stream>>>(
        Pb, slot4, (void*)out, 2048, 2048, 2048, 1024,
        (long long)2048 * 2048, (long long)1024 * 2048, (long long)2048 * 1024, 4);
}

// Round 20
// 314.185 us; speedup vs baseline: 1.0643x; 1.0643x over previous
//
#include <hip/hip_runtime.h>
#include <hip/hip_fp16.h>
#include <math.h>

typedef _Float16 f16;
typedef _Float16 f16x4 __attribute__((ext_vector_type(4)));
typedef _Float16 f16x8 __attribute__((ext_vector_type(8)));
typedef float f32x4 __attribute__((ext_vector_type(4)));
typedef float f32x4e __attribute__((ext_vector_type(4)));

#define GLOAD_LDS16(g, l)                                                                  \
    __builtin_amdgcn_global_load_lds((const __attribute__((address_space(1))) void*)(g),   \
                                     (__attribute__((address_space(3))) void*)(l), 16, 0, 0)

__device__ __forceinline__ void cast16(const float* __restrict__ src, f16* __restrict__ dst,
                                       long long i)
{
    const f32x4e* sp = (const f32x4e*)(src + i * 16);
    f32x4e a = __builtin_nontemporal_load(sp + 0);
    f32x4e b = __builtin_nontemporal_load(sp + 1);
    f32x4e c = __builtin_nontemporal_load(sp + 2);
    f32x4e d4 = __builtin_nontemporal_load(sp + 3);
    f16x8 lo = {(f16)a[0], (f16)a[1], (f16)a[2], (f16)a[3],
                (f16)b[0], (f16)b[1], (f16)b[2], (f16)b[3]};
    f16x8 hi = {(f16)c[0], (f16)c[1], (f16)c[2], (f16)c[3],
                (f16)d4[0], (f16)d4[1], (f16)d4[2], (f16)d4[3]};
    f16x8* dp = (f16x8*)(dst + i * 16);
    dp[0] = lo;
    dp[1] = hi;
}

// W prep: z=0/1 transpose-cast Wq->whA, Wk->whB (dst[h][o] = src[o][h]);
// z=2: plain cast Wv -> whC.  Grid dim3(16,16,3), 256 threads.
__global__ __launch_bounds__(256) void prep_w_kernel(const float* __restrict__ Wq,
                                                     const float* __restrict__ Wk,
                                                     const float* __restrict__ Wv,
                                                     f16* __restrict__ dA,
                                                     f16* __restrict__ dB,
                                                     f16* __restrict__ dC)
{
    __shared__ f16 tile[64][72];
    const int z = blockIdx.z;
    const int t = threadIdx.x;
    if (z == 2) {
        const long long i = (long long)(blockIdx.y * 16 + blockIdx.x) * 256 + t;  // < 65536
        cast16(Wv, dC, i);
        return;
    }
    const float* src = z ? Wk : Wq;
    f16* dst = z ? dB : dA;
    const int h0 = blockIdx.x * 64, o0 = blockIdx.y * 64;
    const int r = t >> 2, c = (t & 3) * 16;
    const float* sp = src + (long long)(o0 + r) * 1024 + h0 + c;
    float4 v0 = *(const float4*)(sp + 0);
    float4 v1 = *(const float4*)(sp + 4);
    float4 v2 = *(const float4*)(sp + 8);
    float4 v3 = *(const float4*)(sp + 12);
    *(f16x4*)&tile[r][c]      = (f16x4){(f16)v0.x, (f16)v0.y, (f16)v0.z, (f16)v0.w};
    *(f16x4*)&tile[r][c + 4]  = (f16x4){(f16)v1.x, (f16)v1.y, (f16)v1.z, (f16)v1.w};
    *(f16x4*)&tile[r][c + 8]  = (f16x4){(f16)v2.x, (f16)v2.y, (f16)v2.z, (f16)v2.w};
    *(f16x4*)&tile[r][c + 12] = (f16x4){(f16)v3.x, (f16)v3.y, (f16)v3.z, (f16)v3.w};
    __syncthreads();
    f16 buf[16];
#pragma unroll
    for (int j = 0; j < 16; j++) buf[j] = tile[c + j][r];
    f16* dp = dst + (long long)(h0 + r) * 1024 + o0 + c;
    *(f16x8*)(dp)     = *(f16x8*)&buf[0];
    *(f16x8*)(dp + 8) = *(f16x8*)&buf[8];
}

// Fused: z=0 cast Xk->dXk, z=1 cast Xv->dXv (4096 blocks each, exact);
// z=2: M = WqT @ WkT^T (1024^2, NT, 128x128 tiles / BK=32 / 4 waves, 64 blocks).
__global__ __launch_bounds__(256) void fused_cast_m_kernel(
    const float* __restrict__ Xk, const float* __restrict__ Xv,
    f16* __restrict__ dXk, f16* __restrict__ dXv,
    const f16* __restrict__ whA, const f16* __restrict__ whB, f16* __restrict__ whD)
{
    __shared__ __align__(16) f16 msmem[128 * 32 * 2];   // 16 KB (z=2 only)
    const int z = blockIdx.z;
    const int tid = threadIdx.x;
    if (z == 0) { cast16(Xk, dXk, (long long)blockIdx.x * 256 + tid); return; }
    if (z == 1) { cast16(Xv, dXv, (long long)blockIdx.x * 256 + tid); return; }
    if (blockIdx.x >= 64) return;   // uniform block exit, before any barrier

    const int b = blockIdx.x;
    const int by = b >> 3, bx = b & 7;
    const char* pA = (const char*)(whA + (long long)by * 128 * 1024);
    const char* pB = (const char*)(whB + (long long)bx * 128 * 1024);
    const int w = tid >> 6, l = tid & 63;
    const int wr = w >> 1, wc = w & 1;
    f32x4 acc[4][4];
#pragma unroll
    for (int i = 0; i < 4; i++)
#pragma unroll
        for (int j = 0; j < 4; j++) acc[i][j] = (f32x4){0.f, 0.f, 0.f, 0.f};
    const int lr = l & 15, lkb = (l >> 4) * 16;

    for (int t = 0; t < 32; ++t) {
        const long long kb = (long long)t * 64;   // 32 f16 = 64 B per row
#pragma unroll
        for (int i = 0; i < 2; i++) {
            const int c = i * 256 + tid;
            const int row = c >> 2;
            const int col = ((c & 3) * 16) ^ ((row & 3) << 4);
            GLOAD_LDS16(pA + (long long)row * 2048 + kb + col, &msmem[(long long)c * 8]);
            GLOAD_LDS16(pB + (long long)row * 2048 + kb + col, &msmem[4096 + (long long)c * 8]);
        }
        __syncthreads();
        f16x8 af[4], bf[4];
#pragma unroll
        for (int f = 0; f < 4; f++) {
            const int ra = wr * 64 + f * 16 + lr;
            const int rb = wc * 64 + f * 16 + lr;
            af[f] = *(const f16x8*)((const char*)&msmem[0] + ra * 64 + (lkb ^ ((ra & 3) << 4)));
            bf[f] = *(const f16x8*)((const char*)&msmem[4096] + rb * 64 + (lkb ^ ((rb & 3) << 4)));
        }
#pragma unroll
        for (int fq = 0; fq < 4; fq++)
#pragma unroll
            for (int fc = 0; fc < 4; fc++)
                acc[fq][fc] = __builtin_amdgcn_mfma_f32_16x16x32_f16(af[fq], bf[fc], acc[fq][fc], 0, 0, 0);
        __syncthreads();
    }
    const int rowl = (l >> 4) * 4;
#pragma unroll
    for (int fq = 0; fq < 4; fq++)
#pragma unroll
        for (int fc = 0; fc < 4; fc++)
#pragma unroll
            for (int i = 0; i < 4; i++)
                whD[(long long)(by * 128 + wr * 64 + fq * 16 + rowl + i) * 1024 +
                    bx * 128 + wc * 64 + fc * 16 + lr] = (f16)acc[fq][fc][i];
}

// ============================================================================
// 256x128 tile NT GEMM, BK=64, 512 threads (8 waves 4Mx2N), SINGLE-buffered
// 48 KiB f16 LDS (m97 regime, r10-r18-proven: ~953 TF, 0 bank conflicts).
// TRANSC=1: epilogue writes C transposed per-batch (vT[b][o][s]) via LDS retile.
// OUTF16=0 epilogue uses non-temporal stores.
// XQCAST=1: grid dim3(2048,1,2); z=1 plane casts Xq f32->f16 (512 thr x 16 el
//   x 2048 blk = 16M, exact); z=0 plane is the GEMM with nwg pinned to 512
//   (blocks >= 512 exit uniformly before any barrier).  Planes data-disjoint.
// C[M,N] = A[M,K](f16) * B[N,K](f16)^T.
// ============================================================================
template <int OUTF16, int TRANSC, int XQCAST>
__global__ __launch_bounds__(512, 2) void gemm_nt_k(
    const f16* __restrict__ Ab, const f16* __restrict__ Bb, void* __restrict__ Cb,
    int K, int lda, int ldb, int ldc,
    long long sA, long long sB, long long sC, int gx,
    const float* __restrict__ xq_src, f16* __restrict__ xq_dst)
{
    __shared__ __align__(16) f16 smem[256 * 64 + 128 * 64];
    constexpr int B_OFF_E = 256 * 64;
    constexpr int B_OFF_B = B_OFF_E * 2;

    const int tid = threadIdx.x;
    if (XQCAST) {
        if (blockIdx.z == 1) { cast16(xq_src, xq_dst, (long long)blockIdx.x * 512 + tid); return; }
        if (blockIdx.x >= 512) return;   // uniform exit, before any barrier
    }

    const int nwg = XQCAST ? 512 : gridDim.x;
    const int swz = (blockIdx.x & 7) * (nwg >> 3) + (blockIdx.x >> 3);
    const int bx = swz % gx, by = swz / gx;

    const int z = XQCAST ? 0 : blockIdx.z;
    const char* pA = (const char*)(Ab + z * sA + (long long)by * 256 * lda);
    const char* pB = (const char*)(Bb + z * sB + (long long)bx * 128 * ldb);
    const long long lda2 = (long long)lda * 2, ldb2 = (long long)ldb * 2;

    const int w = tid >> 6, l = tid & 63;
    const int wr = w >> 1, wc = w & 1;

    f32x4 acc[4][4];
#pragma unroll
    for (int i = 0; i < 4; i++)
#pragma unroll
        for (int j = 0; j < 4; j++) acc[i][j] = (f32x4){0.f, 0.f, 0.f, 0.f};

    const int lr = l & 15;
    const int lkb = (l >> 4) * 16;

#define FRAG_A16(row, kbyte)                                                              \
    (*(const f16x8*)((const char*)&smem[0] + ((row) * 128) + ((kbyte) ^ (((row) & 7) << 4))))
#define FRAG_B(row, kbyte)                                                                \
    (*(const f16x8*)((const char*)&smem[0] + B_OFF_B + ((row) * 128) + ((kbyte) ^ (((row) & 7) << 4))))

    const int nt = K >> 6;
    for (int t = 0; t < nt; ++t) {
        const long long kb = (long long)t * 128;
#pragma unroll
        for (int i = 0; i < 4; i++) {
            const int c = i * 512 + tid;
            const int row = c >> 3;
            const int col = ((c & 7) * 16) ^ ((row & 7) << 4);
            GLOAD_LDS16(pA + (long long)row * lda2 + kb + col, &smem[(long long)c * 8]);
        }
#pragma unroll
        for (int i = 0; i < 2; i++) {
            const int c = i * 512 + tid;
            const int row = c >> 3;
            const int col = ((c & 7) * 16) ^ ((row & 7) << 4);
            GLOAD_LDS16(pB + (long long)row * ldb2 + kb + col, &smem[B_OFF_E + (long long)c * 8]);
        }
        __syncthreads();

        f16x8 bf[4][2], af[4][2];
#pragma unroll
        for (int fc = 0; fc < 4; fc++)
#pragma unroll
            for (int ks = 0; ks < 2; ks++)
                bf[fc][ks] = FRAG_B(wc * 64 + fc * 16 + lr, ks * 64 + lkb);
#pragma unroll
        for (int fq = 0; fq < 4; fq++)
#pragma unroll
            for (int ks = 0; ks < 2; ks++)
                af[fq][ks] = FRAG_A16(wr * 64 + fq * 16 + lr, ks * 64 + lkb);

#pragma unroll
        for (int fq = 0; fq < 4; fq++)
#pragma unroll
            for (int fc = 0; fc < 4; fc++)
#pragma unroll
                for (int ks = 0; ks < 2; ks++)
                    acc[fq][fc] = __builtin_amdgcn_mfma_f32_16x16x32_f16(
                        af[fq][ks], bf[fc][ks], acc[fq][fc], 0, 0, 0);

        __syncthreads();
    }
#undef FRAG_A16
#undef FRAG_B

    const int row_l = (l >> 4) * 4;
    const long long gr0 = (long long)by * 256 + wr * 64;
    const int gc0 = bx * 128 + wc * 64;

    if (TRANSC) {
        const long long blk_r0 = (long long)by * 256;
        const int b = (int)(blk_r0 >> 11);
        const int s_base = (int)(blk_r0 & 2047);
        f16* vTp = (f16*)Cb + (long long)b * 1024 * 2048;
#pragma unroll
        for (int h = 0; h < 2; h++) {
            __syncthreads();
            if ((wr >> 1) == h) {
                const int s64 = (wr & 1) * 64;
#pragma unroll
                for (int fq = 0; fq < 4; fq++)
#pragma unroll
                    for (int fc = 0; fc < 4; fc++)
#pragma unroll
                        for (int i = 0; i < 4; i++)
                            smem[(wc * 64 + fc * 16 + lr) * 136 + s64 + fq * 16 + row_l + i] =
                                (f16)acc[fq][fc][i];
            }
            __syncthreads();
#pragma unroll
            for (int j = 0; j < 4; j++) {
                const int c = j * 512 + tid;
                const int o = c >> 4, s8 = (c & 15) * 8;
                f16x8 vv = *(const f16x8*)&smem[o * 136 + s8];
                *(f16x8*)&vTp[((long long)(bx * 128 + o)) * 2048 + s_base + h * 128 + s8] = vv;
            }
        }
    } else if (OUTF16) {
        f16* C = (f16*)Cb + z * sC;
#pragma unroll
        for (int fq = 0; fq < 4; fq++)
#pragma unroll
            for (int fc = 0; fc < 4; fc++)
#pragma unroll
                for (int i = 0; i < 4; i++)
                    C[(gr0 + fq * 16 + row_l + i) * ldc + gc0 + fc * 16 + lr] = (f16)acc[fq][fc][i];
    } else {
        float* C = (float*)Cb + z * sC;
#pragma unroll
        for (int fq = 0; fq < 4; fq++)
#pragma unroll
            for (int fc = 0; fc < 4; fc++)
#pragma unroll
                for (int i = 0; i < 4; i++)
                    __builtin_nontemporal_store(
                        acc[fq][fc][i],
                        &C[(gr0 + fq * 16 + row_l + i) * ldc + gc0 + fc * 16 + lr]);
    }
}

__device__ __forceinline__ float wred_max(float v) {
#pragma unroll
    for (int o = 32; o > 0; o >>= 1) v = fmaxf(v, __shfl_xor(v, o));
    return v;
}
__device__ __forceinline__ float wred_sum(float v) {
#pragma unroll
    for (int o = 32; o > 0; o >>= 1) v += __shfl_xor(v, o);
    return v;
}

// In-place masked softmax over each 2048-wide score row (fp16).
__global__ __launch_bounds__(256) void softmax_kernel(f16* __restrict__ Sm, const int* __restrict__ mask)
{
    const long long row = blockIdx.x;
    const int b = (int)(row >> 11);
    f16* Srow = Sm + row * 2048;
    const int* mrow = mask + b * 2048;
    const int t = threadIdx.x;
    const int w = t >> 6, l = t & 63;

    f16x8 sv = *(const f16x8*)(Srow + t * 8);
    int4 m0 = *(const int4*)(mrow + t * 8);
    int4 m1 = *(const int4*)(mrow + t * 8 + 4);
    int mk[8] = {m0.x, m0.y, m0.z, m0.w, m1.x, m1.y, m1.z, m1.w};
    float v[8];
#pragma unroll
    for (int j = 0; j < 8; j++) v[j] = (float)sv[j];

    float mx = -INFINITY;
#pragma unroll
    for (int j = 0; j < 8; j++) if (mk[j]) mx = fmaxf(mx, v[j]);
    mx = wred_max(mx);
    __shared__ float redm[4], reds[4];
    if (l == 0) redm[w] = mx;
    __syncthreads();
    mx = fmaxf(fmaxf(redm[0], redm[1]), fmaxf(redm[2], redm[3]));

    if (mx == -INFINITY) {
        // reference: all scores == MASK_FILL -> softmax is exactly uniform
        const f16 u = (f16)(1.0f / 2048.0f);
        f16x8 pv;
#pragma unroll
        for (int j = 0; j < 8; j++) pv[j] = u;
        *(f16x8*)(Srow + t * 8) = pv;
        return;
    }

    float e[8];
    float s = 0.f;
#pragma unroll
    for (int j = 0; j < 8; j++) { e[j] = mk[j] ? expf(v[j] - mx) : 0.f; s += e[j]; }
    s = wred_sum(s);
    if (l == 0) reds[w] = s;
    __syncthreads();
    s = reds[0] + reds[1] + reds[2] + reds[3];
    const float inv = 1.0f / s;
    f16x8 pv;
#pragma unroll
    for (int j = 0; j < 8; j++) pv[j] = (f16)(e[j] * inv);
    *(f16x8*)(Srow + t * 8) = pv;
}

extern "C" void kernel_launch(void* const* d_in, const int* in_sizes, int n_in,
                              void* d_out, int out_size, void* d_ws, size_t ws_size,
                              hipStream_t stream)
{
    const float* query = (const float*)d_in[0];
    const float* keyi  = (const float*)d_in[1];
    const float* value = (const float*)d_in[2];
    const float* Wq    = (const float*)d_in[3];
    const float* Wk    = (const float*)d_in[4];
    const float* Wv    = (const float*)d_in[5];
    const int*   mask  = (const int*)d_in[6];
    float* out = (float*)d_out;

    // Algebra (r14-proven): S = Xq (Wq^T Wk) Xk^T.  M = Wq^T Wk:
    //   k' = Xk @ M^T ;  S = Xq @ k'^T  — no q-projection.
    // ws: 5 slots of SH f16 = 167.8 MB.  Lifetimes:
    //   slot0: Xk (dead after k'-proj) -> P-low
    //   slot1: wh = [WqT|WkT|Wv|M] f16 (8 MB, dead after k'-proj) -> P-high
    //   slot2: Xq (cast fused into the k' dispatch — late, r15 locality)
    //   slot3: Xv (dead after v-proj) -> k'
    //   slot4: vT (v-proj TRANSC epilogue)
    const long long SH = (long long)8 * 2048 * 1024;
    f16* slot0 = (f16*)d_ws;
    f16* slot1 = slot0 + SH;
    f16* slot2 = slot0 + 2 * SH;
    f16* slot3 = slot0 + 3 * SH;
    f16* slot4 = slot0 + 4 * SH;
    const long long M1 = 1024 * 1024;
    f16* whA = slot1;            // WqT f16  [h][o]
    f16* whB = slot1 + M1;       // WkT f16  [h][o]
    f16* whC = slot1 + 2 * M1;   // Wv  f16  [o][h]
    f16* whD = slot1 + 3 * M1;   // M = Wq^T Wk, f16 [j][h]
    f16* Pb  = slot0;            // 8*2048*2048 f16 = 2*SH (slot0 + slot1)

    const long long zero = 0;

    // 0) W prep: WqT, WkT (transpose-cast) + Wv cast — one dispatch
    prep_w_kernel<<<dim3(16, 16, 3), 256, 0, stream>>>(Wq, Wk, Wv, whA, whB, whC);
    // 1) fused: Xk -> slot0, Xv -> slot3 casts  ∥  M = WqT @ WkT^T -> whD
    fused_cast_m_kernel<<<dim3(4096, 1, 3), 256, 0, stream>>>(
        keyi, value, slot0, slot3, whA, whB, whD);
    // 2) v-proj with fused transpose: vT -> slot4  (A = Xv, B = Wv)
    gemm_nt_k<1, 1, 0><<<dim3(512, 1, 1), 512, 0, stream>>>(
        slot3, whC, (void*)slot4, 1024, 1024, 1024, 2048, zero, zero, zero, 8,
        nullptr, nullptr);
    // 3) fused: k' = Xk @ M^T -> slot3 (Xv dead)  ∥  Xq cast -> slot2
    gemm_nt_k<1, 0, 1><<<dim3(2048, 1, 2), 512, 0, stream>>>(
        slot0, whD, (void*)slot3, 1024, 1024, 1024, 1024, zero, zero, zero, 8,
        query, slot2);
    // 4) S = Xq @ k'^T per batch -> P (slot0|slot1; Xk and wh dead)
    gemm_nt_k<1, 0, 0><<<dim3(128, 1, 8), 512, 0, stream>>>(
        slot2, slot3, (void*)Pb, 1024, 1024, 1024, 2048,
        (long long)2048 * 1024, (long long)2048 * 1024, (long long)2048 * 2048, 16,
        nullptr, nullptr);
    // 5) P = masked softmax(S), in place
    softmax_kernel<<<dim3(16384), 256, 0, stream>>>(Pb, mask);
    // 6) context = P @ vT^T  (f32 out, non-temporal stores)
    gemm_nt_k<0, 0, 0><<<dim3(64, 1, 8), 512, 0, stream>>>(
        Pb, slot4, (void*)out, 2048, 2048, 2048, 1024,
        (long long)2048 * 2048, (long long)1024 * 2048, (long long)2048 * 1024, 8,
        nullptr, nullptr);
}